// Round 1
// baseline (35.651 us; speedup 1.0000x reference)
//
#include <hip/hip_runtime.h>

// out[b,c,h,w] = x[b,c,h,w] + emb[(h*16)/64, (w*16)/64, c]
//   x:   [16, 384, 64, 64] fp32 (flat 25,165,824)
//   emb: [1, 16, 16, 384]  fp32 (flat 98,304)  -- L2-resident, reuse 256x
// Vectorized float4 along w: each vector has constant (c, h, w/4) -> one
// scalar emb load broadcast to all 4 lanes. Pure streaming add, HBM-bound.

__global__ __launch_bounds__(256) void spatial_emb_add_kernel(
    const float4* __restrict__ x,
    const float* __restrict__ emb,
    float4* __restrict__ out,
    int nvec) {
    int idx = blockIdx.x * blockDim.x + threadIdx.x;
    int stride = gridDim.x * blockDim.x;
    for (int v = idx; v < nvec; v += stride) {
        unsigned f = (unsigned)v << 2;          // flat element index
        unsigned w0 = f & 63u;                  // w of first lane (mult of 4)
        unsigned h  = (f >> 6) & 63u;           // h
        unsigned c  = (f >> 12) % 384u;         // channel (magic-mul)
        // emb index: ((h/4)*16 + (w0/4)) * 384 + c
        float e = emb[(((h >> 2) << 4) + (w0 >> 2)) * 384u + c];
        float4 xv = x[v];
        float4 o;
        o.x = xv.x + e;
        o.y = xv.y + e;
        o.z = xv.z + e;
        o.w = xv.w + e;
        out[v] = o;
    }
}

extern "C" void kernel_launch(void* const* d_in, const int* in_sizes, int n_in,
                              void* d_out, int out_size, void* d_ws, size_t ws_size,
                              hipStream_t stream) {
    const float4* x  = (const float4*)d_in[0];
    const float*  emb = (const float*)d_in[1];
    float4* out = (float4*)d_out;

    const int nvec = out_size / 4;   // 25,165,824 / 4 = 6,291,456 float4s

    const int block = 256;
    const int grid = 2048;           // grid-stride; ~12 vectors/thread
    spatial_emb_add_kernel<<<grid, block, 0, stream>>>(x, emb, out, nvec);
}